// Round 2
// baseline (495.877 us; speedup 1.0000x reference)
//
#include <hip/hip_runtime.h>
#include <hip/hip_bf16.h>
#include <cstdint>
#include <cstddef>

#define BB 4
#define NN 1024
#define INDIM 128
#define DD 512
#define HH 8
#define EE 4
#define LL 3
#define HDIM 64

typedef __bf16 bf16x8 __attribute__((ext_vector_type(8)));
typedef float f32x4 __attribute__((ext_vector_type(4)));

__device__ __forceinline__ unsigned short f2b(float f) {
    union { float f; unsigned int u; } v; v.f = f;
    unsigned int u = v.u;
    unsigned int r = (u + 0x7FFFu + ((u >> 16) & 1u)) >> 16;
    return (unsigned short)r;
}

__device__ __forceinline__ void gl_lds16(const unsigned short* g, unsigned short* l) {
    __builtin_amdgcn_global_load_lds(
        (const __attribute__((address_space(1))) void*)g,
        (__attribute__((address_space(3))) void*)l, 16, 0, 0);
}

// ---------------- weight transpose+convert: W (K x N fp32) -> Wt (N x K bf16) ---------
__device__ __forceinline__ void transpose_tile_body(const float* __restrict__ src,
                                                    unsigned short* __restrict__ dst,
                                                    int K, int Nc) {
    __shared__ float tl[32][33];
    const int n0 = blockIdx.x * 32, k0 = blockIdx.y * 32;
    const int tx = threadIdx.x, ty = threadIdx.y;
#pragma unroll
    for (int r = 0; r < 4; r++) {
        int k = ty + r * 8;
        tl[k][tx] = src[(size_t)(k0 + k) * Nc + n0 + tx];
    }
    __syncthreads();
#pragma unroll
    for (int r = 0; r < 4; r++) {
        int n = ty + r * 8;
        dst[(size_t)(n0 + n) * K + k0 + tx] = f2b(tl[tx][n]);
    }
}

__global__ void k_transpose_in(const float* __restrict__ w, unsigned short* __restrict__ dst) {
    transpose_tile_body(w, dst, INDIM, DD);
}

__global__ void k_transpose_qkvo(const float* __restrict__ qw, const float* __restrict__ kw,
                                 const float* __restrict__ vw, const float* __restrict__ ow,
                                 unsigned short* __restrict__ dst) {
    int zz = blockIdx.z;
    int l = zz >> 2, tsel = zz & 3;
    const float* src = (tsel == 0) ? qw : (tsel == 1) ? kw : (tsel == 2) ? vw : ow;
    src += (size_t)l * DD * DD;
    transpose_tile_body(src, dst + (size_t)zz * DD * DD, DD, DD);
}

// ---------------- fp32 -> bf16 convert (x) ----------------
__global__ void k_convert(const float* __restrict__ src, unsigned short* __restrict__ dst, int n4) {
    int i = blockIdx.x * blockDim.x + threadIdx.x;
    if (i < n4) {
        float4 v = reinterpret_cast<const float4*>(src)[i];
        uint2 o;
        o.x = (unsigned)f2b(v.x) | ((unsigned)f2b(v.y) << 16);
        o.y = (unsigned)f2b(v.z) | ((unsigned)f2b(v.w) << 16);
        reinterpret_cast<uint2*>(dst)[i] = o;
    }
}

// ---------------- bf16 MFMA GEMM (m97 structure): 128x128 tile, global_load_lds -------
// A: M x Kd bf16 row-major. Wt: 512 x Kd bf16 row-major (W transposed).
// 4 waves in 2x2 grid; each wave computes 64x64 via 4x4 fragments of 16x16x32.
__global__ __launch_bounds__(256) void k_gemm(
    const unsigned short* __restrict__ A,
    const unsigned short* __restrict__ Wt0, size_t wstride,
    const float* __restrict__ bias0, const float* __restrict__ bias1, const float* __restrict__ bias2,
    float* __restrict__ outf,
    unsigned short* __restrict__ outb, size_t ostride,
    const float* __restrict__ resid,
    int Kd)
{
    __shared__ __align__(16) unsigned short As[128 * 32];
    __shared__ __align__(16) unsigned short Bs[128 * 32];
    const int tid = threadIdx.x;
    const int lane = tid & 63, wv = tid >> 6;
    const int wr = wv >> 1, wc = wv & 1;
    const int lm = lane & 15, lh = lane >> 4;
    const int m0 = blockIdx.y * 128, n0 = blockIdx.x * 128;
    const int z = blockIdx.z;
    const unsigned short* Wt = Wt0 + (size_t)z * wstride;
    const float* bias = (z == 0) ? bias0 : (z == 1) ? bias1 : bias2;

    f32x4 acc[4][4] = {};

    // staging map: byte offset o = p*4096 + tid*16 into the 8 KB [128][32]bf16 tile.
    // Within a wave o = p*4096 + wv*1024 + lane*16 -> linear in lane (DMA-legal).
    const int o0 = tid * 16;
    const int row0 = o0 >> 6, col0 = (o0 & 63) >> 1;       // p=0: rows 0..63
    const int row1 = row0 + 64;                            // p=1: rows 64..127

    for (int k0 = 0; k0 < Kd; k0 += 32) {
        __syncthreads();
        gl_lds16(A  + (size_t)(m0 + row0) * Kd + k0 + col0, As + (o0 >> 1));
        gl_lds16(A  + (size_t)(m0 + row1) * Kd + k0 + col0, As + 2048 + (o0 >> 1));
        gl_lds16(Wt + (size_t)(n0 + row0) * Kd + k0 + col0, Bs + (o0 >> 1));
        gl_lds16(Wt + (size_t)(n0 + row1) * Kd + k0 + col0, Bs + 2048 + (o0 >> 1));
        __syncthreads();

        bf16x8 af[4], bfg[4];
#pragma unroll
        for (int mi = 0; mi < 4; mi++)
            af[mi] = *reinterpret_cast<const bf16x8*>(&As[(wr * 64 + mi * 16 + lm) * 32 + lh * 8]);
#pragma unroll
        for (int nj = 0; nj < 4; nj++)
            bfg[nj] = *reinterpret_cast<const bf16x8*>(&Bs[(wc * 64 + nj * 16 + lm) * 32 + lh * 8]);
#pragma unroll
        for (int mi = 0; mi < 4; mi++)
#pragma unroll
            for (int nj = 0; nj < 4; nj++)
                acc[mi][nj] = __builtin_amdgcn_mfma_f32_16x16x32_bf16(af[mi], bfg[nj], acc[mi][nj], 0, 0, 0);
    }

#pragma unroll
    for (int mi = 0; mi < 4; mi++) {
#pragma unroll
        for (int nj = 0; nj < 4; nj++) {
#pragma unroll
            for (int r = 0; r < 4; r++) {
                int i = m0 + wr * 64 + mi * 16 + lh * 4 + r;
                int j = n0 + wc * 64 + nj * 16 + lm;
                float val = acc[mi][nj][r] + bias[j];
                size_t oidx = (size_t)i * DD + j;
                if (resid) val += resid[oidx];
                if (outf) outf[oidx] = val;
                if (outb) outb[(size_t)z * ostride + oidx] = f2b(val);
            }
        }
    }
}

// ---------------- V transpose: vb (B*N, D) bf16 -> vt (B,H,HD,N) bf16 ----------------
__global__ __launch_bounds__(256) void k_transpose_v(const unsigned short* __restrict__ vb,
                                                     unsigned short* __restrict__ vt) {
    __shared__ unsigned short tl[64 * 72];
    const int bh = blockIdx.x;
    const int b = bh >> 3, h = bh & 7;
    const int n0 = blockIdx.y * 64;
    const int t = threadIdx.x;
    {
        int n = t >> 2, seg = t & 3;
        const unsigned short* src = vb + ((size_t)b * NN + n0 + n) * DD + h * HDIM + seg * 16;
        int4 c0 = *reinterpret_cast<const int4*>(src);
        int4 c1 = *reinterpret_cast<const int4*>(src + 8);
        *reinterpret_cast<int4*>(&tl[n * 72 + seg * 16]) = c0;
        *reinterpret_cast<int4*>(&tl[n * 72 + seg * 16 + 8]) = c1;
    }
    __syncthreads();
    {
        int d = t & 63, nb = t >> 6;
        union { unsigned short s[8]; int4 v; } pk0, pk1;
#pragma unroll
        for (int q = 0; q < 8; q++) pk0.s[q] = tl[(nb * 16 + q) * 72 + d];
#pragma unroll
        for (int q = 0; q < 8; q++) pk1.s[q] = tl[(nb * 16 + 8 + q) * 72 + d];
        unsigned short* dst = vt + (((size_t)b * HH + h) * HDIM + d) * NN + n0 + nb * 16;
        *reinterpret_cast<int4*>(dst) = pk0.v;
        *reinterpret_cast<int4*>(dst + 8) = pk1.v;
    }
}

// ---------------- fused attention (flash-style, T14 async-stage on edges) -------------
// 8 waves = 8 heads, one block per (b, 16-row i-tile). Edge tile for j+1 is loaded to
// registers before compute of tile j and committed to LDS after the barrier.
__global__ __launch_bounds__(512) void k_attn(
    const unsigned short* __restrict__ qb,
    const unsigned short* __restrict__ kb,
    const unsigned short* __restrict__ vt,
    const float* __restrict__ edges,
    const float* __restrict__ ew,     // (L,E,H)
    const float* __restrict__ ebias,  // (L,H)
    int layer,
    unsigned short* __restrict__ attnob)
{
    __shared__ float e_lds[16 * 64 * EE];         // 16 KB
    __shared__ unsigned short p_lds[HH][16 * 72]; // 18 KB
    const int b = blockIdx.y;
    const int i0 = blockIdx.x * 16;
    const int tid = threadIdx.x;
    const int lane = tid & 63, h = tid >> 6;
    const int lm = lane & 15, lh = lane >> 4;

    const float LOG2E = 1.44269504f;
    const float ew0 = ew[(layer * EE + 0) * HH + h] * LOG2E;
    const float ew1 = ew[(layer * EE + 1) * HH + h] * LOG2E;
    const float ew2 = ew[(layer * EE + 2) * HH + h] * LOG2E;
    const float ew3 = ew[(layer * EE + 3) * HH + h] * LOG2E;
    const float ebh = ebias[layer * HH + h] * LOG2E;
    const float qscale = 0.125f * LOG2E;

    const unsigned short* qrow = qb + ((size_t)(b * NN) + i0 + lm) * DD + h * HDIM + lh * 8;
    const bf16x8 aq0 = *reinterpret_cast<const bf16x8*>(qrow);
    const bf16x8 aq1 = *reinterpret_cast<const bf16x8*>(qrow + 32);

    f32x4 acc[4] = {};
    float mrow[4], lrow[4];
#pragma unroll
    for (int r = 0; r < 4; r++) { mrow[r] = -1e30f; lrow[r] = 0.f; }

    // edge staging map: c = p*512 + tid -> (ii = c>>6, jj = c&63)
    const int ii_a = tid >> 6, jj_a = tid & 63;       // p = 0
    const int ii_b = 8 + ii_a;                        // p = 1
    const size_t erow_a = ((size_t)b * NN + i0 + ii_a) * NN + jj_a;
    const size_t erow_b = ((size_t)b * NN + i0 + ii_b) * NN + jj_a;

    float4 er0 = *reinterpret_cast<const float4*>(&edges[erow_a * EE]);
    float4 er1 = *reinterpret_cast<const float4*>(&edges[erow_b * EE]);
    *reinterpret_cast<float4*>(&e_lds[tid * 4]) = er0;
    *reinterpret_cast<float4*>(&e_lds[(512 + tid) * 4]) = er1;
    __syncthreads();

    for (int j0 = 0; j0 < NN; j0 += 64) {
        const bool pf = (j0 + 64) < NN;
        if (pf) {  // issue next-tile loads: latency hides under compute below
            er0 = *reinterpret_cast<const float4*>(&edges[(erow_a + j0 + 64) * EE]);
            er1 = *reinterpret_cast<const float4*>(&edges[(erow_b + j0 + 64) * EE]);
        }

        // QK^T for 4 j-subtiles of 16
        f32x4 s[4];
#pragma unroll
        for (int jt = 0; jt < 4; jt++) {
            const unsigned short* krow = kb + ((size_t)(b * NN) + j0 + jt * 16 + lm) * DD + h * HDIM + lh * 8;
            bf16x8 bk0 = *reinterpret_cast<const bf16x8*>(krow);
            bf16x8 bk1 = *reinterpret_cast<const bf16x8*>(krow + 32);
            f32x4 t = {};
            t = __builtin_amdgcn_mfma_f32_16x16x32_bf16(aq0, bk0, t, 0, 0, 0);
            t = __builtin_amdgcn_mfma_f32_16x16x32_bf16(aq1, bk1, t, 0, 0, 0);
            s[jt] = t;
        }

        // bias + scale + online softmax in log2 domain (rows i = 4*lh + r, cols j = jt*16 + lm)
        float pval[4][4];
        float corr[4];
#pragma unroll
        for (int r = 0; r < 4; r++) {
            int ii = lh * 4 + r;
            float mt = -1e30f;
#pragma unroll
            for (int jt = 0; jt < 4; jt++) {
                int jj = jt * 16 + lm;
                const float4 ev = *reinterpret_cast<const float4*>(&e_lds[(ii * 64 + jj) * 4]);
                float sv = s[jt][r] * qscale + ev.x * ew0 + ev.y * ew1 + ev.z * ew2 + ev.w * ew3 + ebh;
                pval[r][jt] = sv;
                mt = fmaxf(mt, sv);
            }
            mt = fmaxf(mt, __shfl_xor(mt, 1));
            mt = fmaxf(mt, __shfl_xor(mt, 2));
            mt = fmaxf(mt, __shfl_xor(mt, 4));
            mt = fmaxf(mt, __shfl_xor(mt, 8));
            float mn = fmaxf(mrow[r], mt);
            corr[r] = __builtin_amdgcn_exp2f(mrow[r] - mn);
            mrow[r] = mn;
            float ls = 0.f;
#pragma unroll
            for (int jt = 0; jt < 4; jt++) {
                float pv = __builtin_amdgcn_exp2f(pval[r][jt] - mn);
                pval[r][jt] = pv;
                ls += pv;
            }
            ls += __shfl_xor(ls, 1);
            ls += __shfl_xor(ls, 2);
            ls += __shfl_xor(ls, 4);
            ls += __shfl_xor(ls, 8);
            lrow[r] = lrow[r] * corr[r] + ls;
#pragma unroll
            for (int jt = 0; jt < 4; jt++)
                p_lds[h][ii * 72 + jt * 16 + lm] = f2b(pval[r][jt]);
        }
#pragma unroll
        for (int dt = 0; dt < 4; dt++)
#pragma unroll
            for (int r = 0; r < 4; r++) acc[dt][r] *= corr[r];

        // PV: A = P tile (16 x 64 from LDS), B = Vt rows (d-major, contiguous in j)
#pragma unroll
        for (int kc = 0; kc < 2; kc++) {
            bf16x8 ap = *reinterpret_cast<const bf16x8*>(&p_lds[h][lm * 72 + kc * 32 + lh * 8]);
#pragma unroll
            for (int dt = 0; dt < 4; dt++) {
                const unsigned short* vrow =
                    vt + (((size_t)(b * HH) + h) * HDIM + dt * 16 + lm) * NN + j0 + kc * 32 + lh * 8;
                bf16x8 bv = *reinterpret_cast<const bf16x8*>(vrow);
                acc[dt] = __builtin_amdgcn_mfma_f32_16x16x32_bf16(ap, bv, acc[dt], 0, 0, 0);
            }
        }

        __syncthreads();   // all waves done reading e_lds
        if (pf) {
            *reinterpret_cast<float4*>(&e_lds[tid * 4]) = er0;
            *reinterpret_cast<float4*>(&e_lds[(512 + tid) * 4]) = er1;
        }
        __syncthreads();   // next tile visible
    }

    float inv[4];
#pragma unroll
    for (int r = 0; r < 4; r++) inv[r] = 1.f / lrow[r];
#pragma unroll
    for (int dt = 0; dt < 4; dt++) {
#pragma unroll
        for (int r = 0; r < 4; r++) {
            float val = acc[dt][r] * inv[r];
            attnob[((size_t)(b * NN) + i0 + lh * 4 + r) * DD + h * HDIM + dt * 16 + lm] = f2b(val);
        }
    }
}

// ---------------- final layernorm: one wave per row ----------------
__global__ __launch_bounds__(64) void k_ln(const float* __restrict__ hbuf,
                                           const float* __restrict__ g,
                                           const float* __restrict__ bta,
                                           float* __restrict__ out) {
    const int row = blockIdx.x;
    const int lane = threadIdx.x;
    const float* hr = hbuf + (size_t)row * DD;
    float4 v0 = reinterpret_cast<const float4*>(hr)[lane * 2];
    float4 v1 = reinterpret_cast<const float4*>(hr)[lane * 2 + 1];
    float vals[8] = {v0.x, v0.y, v0.z, v0.w, v1.x, v1.y, v1.z, v1.w};
    float sum = 0.f, sq = 0.f;
#pragma unroll
    for (int q = 0; q < 8; q++) { sum += vals[q]; sq += vals[q] * vals[q]; }
#pragma unroll
    for (int m = 1; m <= 32; m <<= 1) {
        sum += __shfl_xor(sum, m);
        sq += __shfl_xor(sq, m);
    }
    float mu = sum * (1.f / DD);
    float var = sq * (1.f / DD) - mu * mu;
    float rs = rsqrtf(var + 1e-5f);
    const float* gp = g + lane * 8;
    const float* bp = bta + lane * 8;
    float* op = out + (size_t)row * DD + lane * 8;
#pragma unroll
    for (int q = 0; q < 8; q++) op[q] = (vals[q] - mu) * rs * gp[q] + bp[q];
}

extern "C" void kernel_launch(void* const* d_in, const int* in_sizes, int n_in,
                              void* d_out, int out_size, void* d_ws, size_t ws_size,
                              hipStream_t stream) {
    (void)in_sizes; (void)n_in; (void)out_size; (void)ws_size;
    const float* x     = (const float*)d_in[0];
    const float* edges = (const float*)d_in[1];
    const float* in_w  = (const float*)d_in[2];
    const float* in_b  = (const float*)d_in[3];
    const float* qw    = (const float*)d_in[4];
    const float* qbias = (const float*)d_in[5];
    const float* kw    = (const float*)d_in[6];
    const float* kbias = (const float*)d_in[7];
    const float* vw    = (const float*)d_in[8];
    const float* vbias = (const float*)d_in[9];
    const float* ow    = (const float*)d_in[10];
    const float* obias = (const float*)d_in[11];
    const float* ew    = (const float*)d_in[12];
    const float* ebias = (const float*)d_in[13];
    const float* ln_g  = (const float*)d_in[14];
    const float* ln_b  = (const float*)d_in[15];
    float* out = (float*)d_out;

    char* ws = (char*)d_ws;
    size_t off = 0;
    auto alloc = [&](size_t bytes) -> void* {
        void* p = ws + off;
        off += (bytes + 255) & ~(size_t)255;
        return p;
    };
    const size_t M = (size_t)BB * NN;            // 4096
    float*          hbuf  = (float*)         alloc(M * DD * 4);
    unsigned short* hb    = (unsigned short*)alloc(M * DD * 2);
    unsigned short* xb    = (unsigned short*)alloc(M * INDIM * 2);
    unsigned short* wt_in = (unsigned short*)alloc((size_t)DD * INDIM * 2);
    unsigned short* wt    = (unsigned short*)alloc((size_t)12 * DD * DD * 2);
    unsigned short* qkvb  = (unsigned short*)alloc((size_t)3 * M * DD * 2);
    unsigned short* vtb   = (unsigned short*)alloc(M * DD * 2);
    unsigned short* attnob= (unsigned short*)alloc(M * DD * 2);
    const size_t BND = M * DD;

    // weight prep
    k_transpose_in<<<dim3(DD / 32, INDIM / 32), dim3(32, 8), 0, stream>>>(in_w, wt_in);
    k_transpose_qkvo<<<dim3(DD / 32, DD / 32, 12), dim3(32, 8), 0, stream>>>(qw, kw, vw, ow, wt);
    k_convert<<<dim3(512), dim3(256), 0, stream>>>(x, xb, (int)(M * INDIM / 4));

    // input projection: h = x @ in_w + in_b  (writes fp32 h and bf16 hb)
    k_gemm<<<dim3(4, 32, 1), dim3(256), 0, stream>>>(
        xb, wt_in, (size_t)0, in_b, in_b, in_b, hbuf, hb, (size_t)0, (const float*)nullptr, INDIM);

    for (int l = 0; l < LL; l++) {
        // q,k,v projections in one z-batched launch (bf16 outputs)
        k_gemm<<<dim3(4, 32, 3), dim3(256), 0, stream>>>(
            hb, wt + (size_t)(l * 4) * DD * DD, (size_t)DD * DD,
            qbias + l * DD, kbias + l * DD, vbias + l * DD,
            (float*)nullptr, qkvb, BND, (const float*)nullptr, DD);
        // V -> V^T (B,H,HD,N)
        k_transpose_v<<<dim3(32, 16), dim3(256), 0, stream>>>(qkvb + 2 * BND, vtb);
        // fused attention -> attnob (bf16)
        k_attn<<<dim3(64, 4), dim3(512), 0, stream>>>(
            qkvb, qkvb + BND, vtb, edges, ew, ebias, l, attnob);
        // output projection + residual: h = h + attno @ ow + ob (writes h fp32 + hb bf16)
        k_gemm<<<dim3(4, 32, 1), dim3(256), 0, stream>>>(
            attnob, wt + (size_t)(l * 4 + 3) * DD * DD, (size_t)0,
            obias + l * DD, obias + l * DD, obias + l * DD,
            hbuf, hb, (size_t)0, hbuf, DD);
    }

    k_ln<<<dim3((unsigned)M), dim3(64), 0, stream>>>(hbuf, ln_g, ln_b, out);
}

// Round 3
// 389.207 us; speedup vs baseline: 1.2741x; 1.2741x over previous
//
#include <hip/hip_runtime.h>
#include <hip/hip_bf16.h>
#include <cstdint>
#include <cstddef>

#define BB 4
#define NN 1024
#define INDIM 128
#define DD 512
#define HH 8
#define EE 4
#define LL 3
#define HDIM 64

typedef __bf16 bf16x8 __attribute__((ext_vector_type(8)));
typedef float f32x4 __attribute__((ext_vector_type(4)));

__device__ __forceinline__ unsigned short f2b(float f) {
    union { float f; unsigned int u; } v; v.f = f;
    unsigned int u = v.u;
    unsigned int r = (u + 0x7FFFu + ((u >> 16) & 1u)) >> 16;
    return (unsigned short)r;
}
__device__ __forceinline__ float b2f(unsigned int us) {
    union { unsigned int u; float f; } v; v.u = us << 16; return v.f;
}

__device__ __forceinline__ void gl_lds16(const unsigned short* g, unsigned short* l) {
    __builtin_amdgcn_global_load_lds(
        (const __attribute__((address_space(1))) void*)g,
        (__attribute__((address_space(3))) void*)l, 16, 0, 0);
}

// ---------------- weight transpose+convert: W (K x N fp32) -> Wt (N x K bf16) ---------
__device__ __forceinline__ void transpose_tile_body(const float* __restrict__ src,
                                                    unsigned short* __restrict__ dst,
                                                    int K, int Nc) {
    __shared__ float tl[32][33];
    const int n0 = blockIdx.x * 32, k0 = blockIdx.y * 32;
    const int tx = threadIdx.x, ty = threadIdx.y;
#pragma unroll
    for (int r = 0; r < 4; r++) {
        int k = ty + r * 8;
        tl[k][tx] = src[(size_t)(k0 + k) * Nc + n0 + tx];
    }
    __syncthreads();
#pragma unroll
    for (int r = 0; r < 4; r++) {
        int n = ty + r * 8;
        dst[(size_t)(n0 + n) * K + k0 + tx] = f2b(tl[tx][n]);
    }
}

__global__ void k_transpose_in(const float* __restrict__ w, unsigned short* __restrict__ dst) {
    transpose_tile_body(w, dst, INDIM, DD);
}

__global__ void k_transpose_qkvo(const float* __restrict__ qw, const float* __restrict__ kw,
                                 const float* __restrict__ vw, const float* __restrict__ ow,
                                 unsigned short* __restrict__ dst) {
    int zz = blockIdx.z;
    int l = zz >> 2, tsel = zz & 3;
    const float* src = (tsel == 0) ? qw : (tsel == 1) ? kw : (tsel == 2) ? vw : ow;
    src += (size_t)l * DD * DD;
    transpose_tile_body(src, dst + (size_t)zz * DD * DD, DD, DD);
}

// ---------------- fp32 -> bf16 convert (x, edges) ----------------
__global__ void k_convert(const float* __restrict__ src, unsigned short* __restrict__ dst,
                          long long n4) {
    long long stride = (long long)gridDim.x * blockDim.x;
    for (long long i = blockIdx.x * (long long)blockDim.x + threadIdx.x; i < n4; i += stride) {
        float4 v = reinterpret_cast<const float4*>(src)[i];
        uint2 o;
        o.x = (unsigned)f2b(v.x) | ((unsigned)f2b(v.y) << 16);
        o.y = (unsigned)f2b(v.z) | ((unsigned)f2b(v.w) << 16);
        reinterpret_cast<uint2*>(dst)[i] = o;
    }
}

// ---------------- bf16 MFMA GEMM: 128x64 tile, global_load_lds, m97 staging ----------
// A: M x Kd bf16 row-major. Wt: 512 x Kd bf16 row-major (W transposed).
// 4 waves in 2x2 grid; each wave computes 64x32 via 4x2 fragments of 16x16x32.
__global__ __launch_bounds__(256) void k_gemm(
    const unsigned short* __restrict__ A,
    const unsigned short* __restrict__ Wt0, size_t wstride,
    const float* __restrict__ bias0, const float* __restrict__ bias1, const float* __restrict__ bias2,
    float* __restrict__ outf,
    unsigned short* __restrict__ outb, size_t ostride,
    const float* __restrict__ resid,
    int Kd)
{
    __shared__ __align__(16) unsigned short As[128 * 32];
    __shared__ __align__(16) unsigned short Bs[64 * 32];
    const int tid = threadIdx.x;
    const int lane = tid & 63, wv = tid >> 6;
    const int wr = wv >> 1, wc = wv & 1;
    const int lm = lane & 15, lh = lane >> 4;
    const int m0 = blockIdx.y * 128, n0 = blockIdx.x * 64;
    const int z = blockIdx.z;
    const unsigned short* Wt = Wt0 + (size_t)z * wstride;
    const float* bias = (z == 0) ? bias0 : (z == 1) ? bias1 : bias2;

    f32x4 acc[4][2] = {};

    // staging: byte offset o = tid*16; per-wave LDS dest linear in lane (DMA-legal).
    const int o0 = tid * 16;
    const int rowA = o0 >> 6, colA = (o0 & 63) >> 1;   // [**][32] tiles: 64B rows
    for (int k0 = 0; k0 < Kd; k0 += 32) {
        __syncthreads();
        gl_lds16(A  + (size_t)(m0 + rowA) * Kd + k0 + colA, As + (o0 >> 1));
        gl_lds16(A  + (size_t)(m0 + 64 + rowA) * Kd + k0 + colA, As + 2048 + (o0 >> 1));
        gl_lds16(Wt + (size_t)(n0 + rowA) * Kd + k0 + colA, Bs + (o0 >> 1));
        __syncthreads();

        bf16x8 af[4], bfg[2];
#pragma unroll
        for (int mi = 0; mi < 4; mi++)
            af[mi] = *reinterpret_cast<const bf16x8*>(&As[(wr * 64 + mi * 16 + lm) * 32 + lh * 8]);
#pragma unroll
        for (int nj = 0; nj < 2; nj++)
            bfg[nj] = *reinterpret_cast<const bf16x8*>(&Bs[(wc * 32 + nj * 16 + lm) * 32 + lh * 8]);
#pragma unroll
        for (int mi = 0; mi < 4; mi++)
#pragma unroll
            for (int nj = 0; nj < 2; nj++)
                acc[mi][nj] = __builtin_amdgcn_mfma_f32_16x16x32_bf16(af[mi], bfg[nj], acc[mi][nj], 0, 0, 0);
    }

#pragma unroll
    for (int mi = 0; mi < 4; mi++) {
#pragma unroll
        for (int nj = 0; nj < 2; nj++) {
#pragma unroll
            for (int r = 0; r < 4; r++) {
                int i = m0 + wr * 64 + mi * 16 + lh * 4 + r;
                int j = n0 + wc * 32 + nj * 16 + lm;
                float val = acc[mi][nj][r] + bias[j];
                size_t oidx = (size_t)i * DD + j;
                if (resid) val += resid[oidx];
                if (outf) outf[oidx] = val;
                if (outb) outb[(size_t)z * ostride + oidx] = f2b(val);
            }
        }
    }
}

// ---------------- V transpose: vb (B*N, D) bf16 -> vt (B,H,HD,N) bf16 ----------------
__global__ __launch_bounds__(256) void k_transpose_v(const unsigned short* __restrict__ vb,
                                                     unsigned short* __restrict__ vt) {
    __shared__ unsigned short tl[64 * 72];
    const int bh = blockIdx.x;
    const int b = bh >> 3, h = bh & 7;
    const int n0 = blockIdx.y * 64;
    const int t = threadIdx.x;
    {
        int n = t >> 2, seg = t & 3;
        const unsigned short* src = vb + ((size_t)b * NN + n0 + n) * DD + h * HDIM + seg * 16;
        int4 c0 = *reinterpret_cast<const int4*>(src);
        int4 c1 = *reinterpret_cast<const int4*>(src + 8);
        *reinterpret_cast<int4*>(&tl[n * 72 + seg * 16]) = c0;
        *reinterpret_cast<int4*>(&tl[n * 72 + seg * 16 + 8]) = c1;
    }
    __syncthreads();
    {
        int d = t & 63, nb = t >> 6;
        union { unsigned short s[8]; int4 v; } pk0, pk1;
#pragma unroll
        for (int q = 0; q < 8; q++) pk0.s[q] = tl[(nb * 16 + q) * 72 + d];
#pragma unroll
        for (int q = 0; q < 8; q++) pk1.s[q] = tl[(nb * 16 + 8 + q) * 72 + d];
        unsigned short* dst = vt + (((size_t)b * HH + h) * HDIM + d) * NN + n0 + nb * 16;
        *reinterpret_cast<int4*>(dst) = pk0.v;
        *reinterpret_cast<int4*>(dst + 8) = pk1.v;
    }
}

// ---------------- fused attention: barrier-free, 4 heads/block, direct edge loads -----
// One block per (b, 16-row i-tile, head-group of 4). Edges read per-lane from global
// (bf16x4 = uint2 per (i,j)); reuse across waves/blocks served by L1/L2/L3. P bounced
// through per-wave private LDS; no __syncthreads anywhere.
template <int EBF>
__global__ __launch_bounds__(256) void k_attn(
    const unsigned short* __restrict__ qb,
    const unsigned short* __restrict__ kb,
    const unsigned short* __restrict__ vt,
    const void* __restrict__ edges_p,   // EBF: uint2 bf16x4; else float4 fp32
    const float* __restrict__ ew,       // (L,E,H)
    const float* __restrict__ ebias,    // (L,H)
    int layer,
    unsigned short* __restrict__ attnob)
{
    __shared__ unsigned short p_lds[4][16 * 72];  // per-wave private
    const int b = blockIdx.y;
    const int i0 = blockIdx.x * 16;
    const int tid = threadIdx.x;
    const int lane = tid & 63, wv = tid >> 6;
    const int h = blockIdx.z * 4 + wv;
    const int lm = lane & 15, lh = lane >> 4;

    const float LOG2E = 1.44269504f;
    const float ew0 = ew[(layer * EE + 0) * HH + h] * LOG2E;
    const float ew1 = ew[(layer * EE + 1) * HH + h] * LOG2E;
    const float ew2 = ew[(layer * EE + 2) * HH + h] * LOG2E;
    const float ew3 = ew[(layer * EE + 3) * HH + h] * LOG2E;
    const float ebh = ebias[layer * HH + h] * LOG2E;
    const float qscale = 0.125f * LOG2E;

    const unsigned short* qrow = qb + ((size_t)(b * NN) + i0 + lm) * DD + h * HDIM + lh * 8;
    const bf16x8 aq0 = *reinterpret_cast<const bf16x8*>(qrow);
    const bf16x8 aq1 = *reinterpret_cast<const bf16x8*>(qrow + 32);

    f32x4 acc[4] = {};
    float mrow[4], lrow[4];
#pragma unroll
    for (int r = 0; r < 4; r++) { mrow[r] = -1e30f; lrow[r] = 0.f; }

    // per-lane edge row bases (rows i0 + lh*4 + r, starting col lm)
    const uint2*  ebf = (const uint2*)edges_p;
    const float4* ef4 = (const float4*)edges_p;
    size_t erow[4];
#pragma unroll
    for (int r = 0; r < 4; r++)
        erow[r] = ((size_t)b * NN + i0 + lh * 4 + r) * NN + lm;

    for (int j0 = 0; j0 < NN; j0 += 64) {
        // edge values for this tile, straight to registers
        float ebv[4][4][4];
#pragma unroll
        for (int r = 0; r < 4; r++) {
#pragma unroll
            for (int jt = 0; jt < 4; jt++) {
                if (EBF) {
                    uint2 e = ebf[erow[r] + j0 + jt * 16];
                    ebv[r][jt][0] = b2f(e.x & 0xffffu);
                    ebv[r][jt][1] = b2f(e.x >> 16);
                    ebv[r][jt][2] = b2f(e.y & 0xffffu);
                    ebv[r][jt][3] = b2f(e.y >> 16);
                } else {
                    float4 e = ef4[erow[r] + j0 + jt * 16];
                    ebv[r][jt][0] = e.x; ebv[r][jt][1] = e.y;
                    ebv[r][jt][2] = e.z; ebv[r][jt][3] = e.w;
                }
            }
        }

        // QK^T for 4 j-subtiles of 16
        f32x4 s[4];
#pragma unroll
        for (int jt = 0; jt < 4; jt++) {
            const unsigned short* krow = kb + ((size_t)(b * NN) + j0 + jt * 16 + lm) * DD + h * HDIM + lh * 8;
            bf16x8 bk0 = *reinterpret_cast<const bf16x8*>(krow);
            bf16x8 bk1 = *reinterpret_cast<const bf16x8*>(krow + 32);
            f32x4 t = {};
            t = __builtin_amdgcn_mfma_f32_16x16x32_bf16(aq0, bk0, t, 0, 0, 0);
            t = __builtin_amdgcn_mfma_f32_16x16x32_bf16(aq1, bk1, t, 0, 0, 0);
            s[jt] = t;
        }

        // bias + scale + online softmax, log2 domain (row i = lh*4+r, col j = jt*16+lm)
        float pval[4][4];
        float corr[4];
#pragma unroll
        for (int r = 0; r < 4; r++) {
            float mt = -1e30f;
#pragma unroll
            for (int jt = 0; jt < 4; jt++) {
                float sv = s[jt][r] * qscale + ebv[r][jt][0] * ew0 + ebv[r][jt][1] * ew1
                         + ebv[r][jt][2] * ew2 + ebv[r][jt][3] * ew3 + ebh;
                pval[r][jt] = sv;
                mt = fmaxf(mt, sv);
            }
            mt = fmaxf(mt, __shfl_xor(mt, 1));
            mt = fmaxf(mt, __shfl_xor(mt, 2));
            mt = fmaxf(mt, __shfl_xor(mt, 4));
            mt = fmaxf(mt, __shfl_xor(mt, 8));
            float mn = fmaxf(mrow[r], mt);
            corr[r] = __builtin_amdgcn_exp2f(mrow[r] - mn);
            mrow[r] = mn;
            float ls = 0.f;
#pragma unroll
            for (int jt = 0; jt < 4; jt++) {
                float pv = __builtin_amdgcn_exp2f(pval[r][jt] - mn);
                pval[r][jt] = pv;
                ls += pv;
            }
            ls += __shfl_xor(ls, 1);
            ls += __shfl_xor(ls, 2);
            ls += __shfl_xor(ls, 4);
            ls += __shfl_xor(ls, 8);
            lrow[r] = lrow[r] * corr[r] + ls;
            int ii = lh * 4 + r;
#pragma unroll
            for (int jt = 0; jt < 4; jt++)
                p_lds[wv][ii * 72 + jt * 16 + lm] = f2b(pval[r][jt]);
        }
#pragma unroll
        for (int dt = 0; dt < 4; dt++)
#pragma unroll
            for (int r = 0; r < 4; r++) acc[dt][r] *= corr[r];

        // PV: A = P tile (16 x 64 from LDS), B = Vt rows (d-major, contiguous in j)
#pragma unroll
        for (int kc = 0; kc < 2; kc++) {
            bf16x8 ap = *reinterpret_cast<const bf16x8*>(&p_lds[wv][lm * 72 + kc * 32 + lh * 8]);
#pragma unroll
            for (int dt = 0; dt < 4; dt++) {
                const unsigned short* vrow =
                    vt + (((size_t)(b * HH) + h) * HDIM + dt * 16 + lm) * NN + j0 + kc * 32 + lh * 8;
                bf16x8 bv = *reinterpret_cast<const bf16x8*>(vrow);
                acc[dt] = __builtin_amdgcn_mfma_f32_16x16x32_bf16(ap, bv, acc[dt], 0, 0, 0);
            }
        }
    }

    float inv[4];
#pragma unroll
    for (int r = 0; r < 4; r++) inv[r] = 1.f / lrow[r];
#pragma unroll
    for (int dt = 0; dt < 4; dt++) {
#pragma unroll
        for (int r = 0; r < 4; r++) {
            float val = acc[dt][r] * inv[r];
            attnob[((size_t)(b * NN) + i0 + lh * 4 + r) * DD + h * HDIM + dt * 16 + lm] = f2b(val);
        }
    }
}

// ---------------- final layernorm: one wave per row ----------------
__global__ __launch_bounds__(64) void k_ln(const float* __restrict__ hbuf,
                                           const float* __restrict__ g,
                                           const float* __restrict__ bta,
                                           float* __restrict__ out) {
    const int row = blockIdx.x;
    const int lane = threadIdx.x;
    const float* hr = hbuf + (size_t)row * DD;
    float4 v0 = reinterpret_cast<const float4*>(hr)[lane * 2];
    float4 v1 = reinterpret_cast<const float4*>(hr)[lane * 2 + 1];
    float vals[8] = {v0.x, v0.y, v0.z, v0.w, v1.x, v1.y, v1.z, v1.w};
    float sum = 0.f, sq = 0.f;
#pragma unroll
    for (int q = 0; q < 8; q++) { sum += vals[q]; sq += vals[q] * vals[q]; }
#pragma unroll
    for (int m = 1; m <= 32; m <<= 1) {
        sum += __shfl_xor(sum, m);
        sq += __shfl_xor(sq, m);
    }
    float mu = sum * (1.f / DD);
    float var = sq * (1.f / DD) - mu * mu;
    float rs = rsqrtf(var + 1e-5f);
    const float* gp = g + lane * 8;
    const float* bp = bta + lane * 8;
    float* op = out + (size_t)row * DD + lane * 8;
#pragma unroll
    for (int q = 0; q < 8; q++) op[q] = (vals[q] - mu) * rs * gp[q] + bp[q];
}

extern "C" void kernel_launch(void* const* d_in, const int* in_sizes, int n_in,
                              void* d_out, int out_size, void* d_ws, size_t ws_size,
                              hipStream_t stream) {
    (void)in_sizes; (void)n_in; (void)out_size;
    const float* x     = (const float*)d_in[0];
    const float* edges = (const float*)d_in[1];
    const float* in_w  = (const float*)d_in[2];
    const float* in_b  = (const float*)d_in[3];
    const float* qw    = (const float*)d_in[4];
    const float* qbias = (const float*)d_in[5];
    const float* kw    = (const float*)d_in[6];
    const float* kbias = (const float*)d_in[7];
    const float* vw    = (const float*)d_in[8];
    const float* vbias = (const float*)d_in[9];
    const float* ow    = (const float*)d_in[10];
    const float* obias = (const float*)d_in[11];
    const float* ew    = (const float*)d_in[12];
    const float* ebias = (const float*)d_in[13];
    const float* ln_g  = (const float*)d_in[14];
    const float* ln_b  = (const float*)d_in[15];
    float* out = (float*)d_out;

    char* ws = (char*)d_ws;
    size_t off = 0;
    auto alloc = [&](size_t bytes) -> void* {
        void* p = ws + off;
        off += (bytes + 255) & ~(size_t)255;
        return p;
    };
    const size_t M = (size_t)BB * NN;            // 4096
    float*          hbuf  = (float*)         alloc(M * DD * 4);
    unsigned short* hb    = (unsigned short*)alloc(M * DD * 2);
    unsigned short* xb    = (unsigned short*)alloc(M * INDIM * 2);
    unsigned short* wt_in = (unsigned short*)alloc((size_t)DD * INDIM * 2);
    unsigned short* wt    = (unsigned short*)alloc((size_t)12 * DD * DD * 2);
    unsigned short* qkvb  = (unsigned short*)alloc((size_t)3 * M * DD * 2);
    unsigned short* vtb   = (unsigned short*)alloc(M * DD * 2);
    unsigned short* attnob= (unsigned short*)alloc(M * DD * 2);
    const size_t edgeElems = (size_t)BB * NN * NN * EE;       // 16.8M
    unsigned short* ebf   = (unsigned short*)alloc(edgeElems * 2);  // 33.5 MB
    const bool use_ebf = (off <= ws_size);
    const size_t BND = M * DD;

    // weight prep + input/edge conversion
    k_transpose_in<<<dim3(DD / 32, INDIM / 32), dim3(32, 8), 0, stream>>>(in_w, wt_in);
    k_transpose_qkvo<<<dim3(DD / 32, DD / 32, 12), dim3(32, 8), 0, stream>>>(qw, kw, vw, ow, wt);
    k_convert<<<dim3(512), dim3(256), 0, stream>>>(x, xb, (long long)(M * INDIM / 4));
    if (use_ebf)
        k_convert<<<dim3(2048), dim3(256), 0, stream>>>(edges, ebf, (long long)(edgeElems / 4));

    // input projection: h = x @ in_w + in_b  (writes fp32 h and bf16 hb)
    k_gemm<<<dim3(8, 32, 1), dim3(256), 0, stream>>>(
        xb, wt_in, (size_t)0, in_b, in_b, in_b, hbuf, hb, (size_t)0, (const float*)nullptr, INDIM);

    for (int l = 0; l < LL; l++) {
        // q,k,v projections in one z-batched launch (bf16 outputs)
        k_gemm<<<dim3(8, 32, 3), dim3(256), 0, stream>>>(
            hb, wt + (size_t)(l * 4) * DD * DD, (size_t)DD * DD,
            qbias + l * DD, kbias + l * DD, vbias + l * DD,
            (float*)nullptr, qkvb, BND, (const float*)nullptr, DD);
        // V -> V^T (B,H,HD,N)
        k_transpose_v<<<dim3(32, 16), dim3(256), 0, stream>>>(qkvb + 2 * BND, vtb);
        // fused attention -> attnob (bf16)
        if (use_ebf)
            k_attn<1><<<dim3(64, 4, 2), dim3(256), 0, stream>>>(
                qkvb, qkvb + BND, vtb, (const void*)ebf, ew, ebias, l, attnob);
        else
            k_attn<0><<<dim3(64, 4, 2), dim3(256), 0, stream>>>(
                qkvb, qkvb + BND, vtb, (const void*)edges, ew, ebias, l, attnob);
        // output projection + residual: h = h + attno @ ow + ob (writes h fp32 + hb bf16)
        k_gemm<<<dim3(8, 32, 1), dim3(256), 0, stream>>>(
            attnob, wt + (size_t)(l * 4 + 3) * DD * DD, (size_t)0,
            obias + l * DD, obias + l * DD, obias + l * DD,
            hbuf, hb, (size_t)0, hbuf, DD);
    }

    k_ln<<<dim3((unsigned)M), dim3(64), 0, stream>>>(hbuf, ln_g, ln_b, out);
}